// Round 1
// baseline (572.855 us; speedup 1.0000x reference)
//
#include <hip/hip_runtime.h>
#include <hip/hip_bf16.h>

typedef __attribute__((ext_vector_type(4))) float f32x4;
typedef __attribute__((ext_vector_type(8))) short bf16x8;   // 8 bf16 = 4 VGPR (MFMA A/B operand)
typedef __attribute__((ext_vector_type(4))) int   i32x4;
typedef __attribute__((ext_vector_type(2))) int   i32x2;

#define HT0 0u
#define GT0 65536u
#define PT0 131072u
#define LG0 135168u
#define K3_LDS 143360
#define QK_SCALE 0.04419417382415922f   // 512^-0.5

static __device__ __forceinline__ unsigned short f2bf(float f) {
    unsigned int u = __builtin_bit_cast(unsigned int, f);
    u += 0x7fffu + ((u >> 16) & 1u);          // RNE
    return (unsigned short)(u >> 16);
}
static __device__ __forceinline__ float bf2f(unsigned short h) {
    unsigned int u = ((unsigned int)h) << 16;
    return __builtin_bit_cast(float, u);
}
static __device__ __forceinline__ f32x4 fzero() {
    f32x4 v; v[0] = 0.f; v[1] = 0.f; v[2] = 0.f; v[3] = 0.f; return v;
}

// ---------------------------------------------------------------------------
// kw_weights: Wqk = wq^T * wk ; Wpv = wproj * wv   (512x512 fp32 -> bf16)
// ---------------------------------------------------------------------------
__global__ __launch_bounds__(256) void kw_weights(
    const float* __restrict__ wq, const float* __restrict__ wk,
    const float* __restrict__ wproj, const float* __restrict__ wv,
    unsigned short* __restrict__ wqk, unsigned short* __restrict__ wpv)
{
    int bx = blockIdx.x;            // 128 blocks: [0,64) -> Wqk, [64,128) -> Wpv
    int mat = bx >> 6;
    int tile = bx & 63;
    int i0 = (tile >> 3) * 64, j0 = (tile & 7) * 64;
    const float* A  = mat ? wproj : wq;
    const float* Bm = mat ? wv : wk;
    unsigned short* Out = mat ? wpv : wqk;
    __shared__ float At[16][64];
    __shared__ float Bt[16][64];
    int tid = threadIdx.x;
    int ty = tid >> 4, tx = tid & 15;
    float acc[4][4] = {};
    for (int k0 = 0; k0 < 512; k0 += 16) {
        if (mat == 0) {
            // At[kk][ii] = wq[k0+kk][i0+ii]   (A^T form)
#pragma unroll
            for (int r = 0; r < 4; ++r) {
                int idx = r * 256 + tid;
                At[idx >> 6][idx & 63] = A[(size_t)(k0 + (idx >> 6)) * 512 + i0 + (idx & 63)];
            }
        } else {
            // At[kk][ii] = wproj[i0+ii][k0+kk]
#pragma unroll
            for (int r = 0; r < 4; ++r) {
                int idx = r * 256 + tid;
                At[idx & 15][idx >> 4] = A[(size_t)(i0 + (idx >> 4)) * 512 + k0 + (idx & 15)];
            }
        }
#pragma unroll
        for (int r = 0; r < 4; ++r) {
            int idx = r * 256 + tid;
            Bt[idx >> 6][idx & 63] = Bm[(size_t)(k0 + (idx >> 6)) * 512 + j0 + (idx & 63)];
        }
        __syncthreads();
#pragma unroll
        for (int kk = 0; kk < 16; ++kk)
#pragma unroll
            for (int i = 0; i < 4; ++i)
#pragma unroll
                for (int j = 0; j < 4; ++j)
                    acc[i][j] += At[kk][ty * 4 + i] * Bt[kk][tx * 4 + j];
        __syncthreads();
    }
#pragma unroll
    for (int i = 0; i < 4; ++i) {
        ushort4 o;
        o.x = f2bf(acc[i][0]); o.y = f2bf(acc[i][1]);
        o.z = f2bf(acc[i][2]); o.w = f2bf(acc[i][3]);
        *(ushort4*)(Out + (size_t)(i0 + ty * 4 + i) * 512 + j0 + tx * 4) = o;
    }
}

// ---------------------------------------------------------------------------
// k_transpose_stats: x[b][c][t][h][w] -> Hraw[pix][t][c] (raw bf16, no norm)
// + per-(b,t) partial sums (sum, sumsq) via atomics.
// block = (bb, h, t-pair); 512 threads; 64KB LDS tile [c][tt][w] XOR-swizzled.
// ---------------------------------------------------------------------------
__global__ __launch_bounds__(512) void k_transpose_stats(
    const float* __restrict__ x, unsigned short* __restrict__ Hraw, float* __restrict__ sums)
{
    int bx = blockIdx.x;                  // 2048 = 4*32*16
    int tp = bx & 15;
    int h  = (bx >> 4) & 31;
    int bb = bx >> 9;
    int t0 = tp * 2;
    int tid = threadIdx.x;
    extern __shared__ char lds[];         // 64KB + 128B reduce scratch
    float* red = (float*)(lds + 65536);

    int tt = (tid >> 3) & 1;              // constant per thread
    int w4 = tid & 7;
    int cb = tid >> 4;                    // 0..31
    float s = 0.f, q = 0.f;
    const unsigned int Kt = (unsigned int)tt * 64u + (unsigned int)w4 * 8u;
#pragma unroll
    for (int it = 0; it < 16; ++it) {
        int c = it * 32 + cb;
        float4 v = *(const float4*)(x + (((size_t)(bb * 512 + c)) * 32 + (t0 + tt)) * 1024 + h * 32 + w4 * 4);
        s += v.x + v.y + v.z + v.w;
        q += v.x * v.x + v.y * v.y + v.z * v.z + v.w * v.w;
        unsigned int p0 = ((unsigned int)f2bf(v.y) << 16) | f2bf(v.x);
        unsigned int p1 = ((unsigned int)f2bf(v.w) << 16) | f2bf(v.z);
        unsigned int Kx = ((unsigned int)((c >> 3) & 31)) << 2;
        unsigned int base = (unsigned int)c * 128u + Kt;
        *(unsigned int*)(lds + ((base + 0u) ^ Kx)) = p0;
        *(unsigned int*)(lds + ((base + 4u) ^ Kx)) = p1;
    }
    // reduce within same-tt lanes (all lane-xor masks except bit 3)
    s += __shfl_xor(s, 1);  q += __shfl_xor(q, 1);
    s += __shfl_xor(s, 2);  q += __shfl_xor(q, 2);
    s += __shfl_xor(s, 4);  q += __shfl_xor(q, 4);
    s += __shfl_xor(s, 16); q += __shfl_xor(q, 16);
    s += __shfl_xor(s, 32); q += __shfl_xor(q, 32);
    int wid = tid >> 6, lane = tid & 63;
    if (lane == 0) { red[wid * 4 + 0] = s; red[wid * 4 + 1] = q; }
    if (lane == 8) { red[wid * 4 + 2] = s; red[wid * 4 + 3] = q; }
    __syncthreads();
    if (tid < 4) {
        float a = 0.f;
#pragma unroll
        for (int w = 0; w < 8; ++w) a += red[w * 4 + tid];
        int f = bb * 32 + t0 + (tid >> 1);
        atomicAdd(&sums[f * 2 + (tid & 1)], a);
    }
    // write Hraw[pix][t][c]: one (pix,t) row (1KB) per wave instruction
#pragma unroll
    for (int rnd = 0; rnd < 8; ++rnd) {
        int row = rnd * 8 + wid;          // 0..63
        int w = row >> 1, ttw = row & 1;
        int c0 = lane * 8;
        unsigned short e[8];
#pragma unroll
        for (int j = 0; j < 8; ++j) {
            int c = c0 + j;
            unsigned int Kx = ((unsigned int)((c >> 3) & 31)) << 2;
            unsigned int off = ((unsigned int)(c * 128 + ttw * 64 + 2 * w)) ^ Kx;
            e[j] = *(const unsigned short*)(lds + off);
        }
        i32x4 ov;
        ov[0] = (int)(((unsigned int)e[1] << 16) | e[0]);
        ov[1] = (int)(((unsigned int)e[3] << 16) | e[2]);
        ov[2] = (int)(((unsigned int)e[5] << 16) | e[4]);
        ov[3] = (int)(((unsigned int)e[7] << 16) | e[6]);
        size_t pix = ((size_t)bb * 32 + h) * 32 + w;
        *(i32x4*)(Hraw + pix * 16384 + (size_t)(t0 + ttw) * 512 + c0) = ov;
    }
}

// ---------------------------------------------------------------------------
__global__ void k_finalize(const float* __restrict__ sums, float* __restrict__ mr) {
    int f = threadIdx.x;                  // 128 frames
    float mean = sums[f * 2] * (1.f / 524288.f);
    float var  = sums[f * 2 + 1] * (1.f / 524288.f) - mean * mean;
    mr[f * 2]     = mean;
    mr[f * 2 + 1] = rsqrtf(var + 1e-6f);
}

// ---------------------------------------------------------------------------
// k_attn helpers
// ---------------------------------------------------------------------------
static __device__ __forceinline__ void mfma16(f32x4 (&acc)[4][4], const bf16x8 (&a)[4], const bf16x8 (&b)[4]) {
#pragma unroll
    for (int mt = 0; mt < 4; ++mt)
#pragma unroll
        for (int nf = 0; nf < 4; ++nf)
            acc[mt][nf] = __builtin_amdgcn_mfma_f32_16x16x32_bf16(a[mt], b[nf], acc[mt][nf], 0, 0, 0);
}
static __device__ __forceinline__ void load_w4(bf16x8 (&a)[4], const unsigned short* wbase, int k0) {
#pragma unroll
    for (int mt = 0; mt < 4; ++mt)
        a[mt] = *(const bf16x8*)(wbase + (size_t)mt * 16 * 512 + k0);
}
static __device__ __forceinline__ void load_h4(bf16x8 (&b)[4], const char* ldsb, int lo, int hi, int k0) {
#pragma unroll
    for (int nf = 0; nf < 4; ++nf) {
        int row = nf * 16 + lo;
        unsigned off = ((unsigned)(row * 1024 + (k0 + hi * 8) * 2)) ^ (((unsigned)(row & 7)) << 4);
        b[nf] = *(const bf16x8*)(ldsb + off);
    }
}

// ---------------------------------------------------------------------------
// k_attn: per block 2 pixels. hT[64][512] bf16 (swz (row&7)<<4) @0;
// gT[64][512] / U[512][64] @64K; pT[2][32][32] bf16 @128K; logits f32 @132K.
// OA written in-place over Hraw (block reads all its H before writing).
// ---------------------------------------------------------------------------
__global__ __launch_bounds__(512, 2) void k_attn(
    const unsigned short* Hraw,
    const unsigned short* __restrict__ Wqk,
    const unsigned short* __restrict__ Wpv,
    const float* __restrict__ gamma, const float* __restrict__ beta,
    const float* __restrict__ mr,
    unsigned short* OA)
{
    extern __shared__ char lds[];
    int tid = threadIdx.x, wid = tid >> 6, lane = tid & 63;
    int lo = lane & 15, hi = lane >> 4;
    int pix0 = blockIdx.x * 2;
    int b_ = pix0 >> 10;                  // both pixels share b

    // ---- phase A: load Hraw + apply LayerNorm affine -> hT ----
    {
        const unsigned short* src = Hraw + (size_t)pix0 * 16384;
#pragma unroll
        for (int it = 0; it < 8; ++it) {
            int chunk = it * 512 + tid;   // 4096 x 16B
            int row = chunk >> 6;
            int col = chunk & 63;
            int t = row & 31;
            float2 mrv = *(const float2*)(mr + ((b_ << 5) + t) * 2);
            i32x4 v = *(const i32x4*)(src + (size_t)chunk * 8);
            int c0 = col * 8;
            float4 g0 = *(const float4*)(gamma + c0);
            float4 g1 = *(const float4*)(gamma + c0 + 4);
            float4 be0 = *(const float4*)(beta + c0);
            float4 be1 = *(const float4*)(beta + c0 + 4);
            float mu = mrv.x, rs = mrv.y;
            i32x4 ov;
            {
                float xa = bf2f((unsigned short)(v[0] & 0xffff));
                float xb = bf2f((unsigned short)((unsigned int)v[0] >> 16));
                ov[0] = (int)((((unsigned int)f2bf((xb - mu) * (rs * g0.y) + be0.y)) << 16) | f2bf((xa - mu) * (rs * g0.x) + be0.x));
            }
            {
                float xa = bf2f((unsigned short)(v[1] & 0xffff));
                float xb = bf2f((unsigned short)((unsigned int)v[1] >> 16));
                ov[1] = (int)((((unsigned int)f2bf((xb - mu) * (rs * g0.w) + be0.w)) << 16) | f2bf((xa - mu) * (rs * g0.z) + be0.z));
            }
            {
                float xa = bf2f((unsigned short)(v[2] & 0xffff));
                float xb = bf2f((unsigned short)((unsigned int)v[2] >> 16));
                ov[2] = (int)((((unsigned int)f2bf((xb - mu) * (rs * g1.y) + be1.y)) << 16) | f2bf((xa - mu) * (rs * g1.x) + be1.x));
            }
            {
                float xa = bf2f((unsigned short)(v[3] & 0xffff));
                float xb = bf2f((unsigned short)((unsigned int)v[3] >> 16));
                ov[3] = (int)((((unsigned int)f2bf((xb - mu) * (rs * g1.w) + be1.w)) << 16) | f2bf((xa - mu) * (rs * g1.z) + be1.z));
            }
            unsigned off = ((unsigned)(row * 1024 + col * 16)) ^ (((unsigned)(row & 7)) << 4);
            *(i32x4*)(lds + HT0 + off) = ov;
        }
    }
    __syncthreads();

    // ---- phase B: g = Wqk * h  (per wave: 64 c-rows x 64 n), write gT[n][c] ----
    {
        f32x4 acc[4][4];
#pragma unroll
        for (int mt = 0; mt < 4; ++mt)
#pragma unroll
            for (int nf = 0; nf < 4; ++nf) acc[mt][nf] = fzero();
        const unsigned short* wbase = Wqk + (size_t)(wid * 64 + lo) * 512 + hi * 8;
        bf16x8 a0[4], b0v[4], a1[4], b1v[4];
        load_w4(a0, wbase, 0);
        load_h4(b0v, lds + HT0, lo, hi, 0);
#pragma unroll 2
        for (int kk = 0; kk < 8; ++kk) {
            int k0 = kk * 64;
            load_w4(a1, wbase, k0 + 32);
            load_h4(b1v, lds + HT0, lo, hi, k0 + 32);
            mfma16(acc, a0, b0v);
            if (kk < 7) {
                load_w4(a0, wbase, k0 + 64);
                load_h4(b0v, lds + HT0, lo, hi, k0 + 64);
            }
            mfma16(acc, a1, b1v);
        }
#pragma unroll
        for (int mt = 0; mt < 4; ++mt)
#pragma unroll
            for (int nf = 0; nf < 4; ++nf) {
                int n = nf * 16 + lo;
                int c0 = wid * 64 + mt * 16 + hi * 4;
                unsigned int w0 = ((unsigned int)f2bf(acc[mt][nf][1]) << 16) | f2bf(acc[mt][nf][0]);
                unsigned int w1 = ((unsigned int)f2bf(acc[mt][nf][3]) << 16) | f2bf(acc[mt][nf][2]);
                unsigned off = ((unsigned)(n * 1024 + c0 * 2)) ^ (((unsigned)(n & 7)) << 4);
                i32x2 pv; pv[0] = (int)w0; pv[1] = (int)w1;
                *(i32x2*)(lds + GT0 + off) = pv;
            }
    }
    __syncthreads();

    // ---- phase C: logits[t][s] = h^T g  (wave -> (p, t-half, s-half)) ----
    {
        int p = wid >> 2, tth = (wid >> 1) & 1, sh = wid & 1;
        int arow = p * 32 + tth * 16 + lo;
        int brow = p * 32 + sh * 16 + lo;
        f32x4 acc = fzero();
#pragma unroll 4
        for (int k0 = 0; k0 < 512; k0 += 32) {
            unsigned aoff = ((unsigned)(arow * 1024 + (k0 + hi * 8) * 2)) ^ (((unsigned)(arow & 7)) << 4);
            unsigned boff = ((unsigned)(brow * 1024 + (k0 + hi * 8) * 2)) ^ (((unsigned)(brow & 7)) << 4);
            bf16x8 a = *(const bf16x8*)(lds + HT0 + aoff);
            bf16x8 b = *(const bf16x8*)(lds + GT0 + boff);
            acc = __builtin_amdgcn_mfma_f32_16x16x32_bf16(a, b, acc, 0, 0, 0);
        }
#pragma unroll
        for (int r = 0; r < 4; ++r) {
            int t = tth * 16 + hi * 4 + r;
            int s = sh * 16 + lo;
            *(float*)(lds + LG0 + (unsigned)(((p * 32 + t) * 32 + s) * 4)) = acc[r] * QK_SCALE;
        }
    }
    __syncthreads();

    // ---- phase D: causal mask + softmax -> pT bf16 ----
    {
        int row = tid >> 3;
        int p = row >> 5, t = row & 31;
        int s0 = (tid & 7) * 4;
        f32x4 v = *(const f32x4*)(lds + LG0 + (unsigned)(((p * 32 + t) * 32 + s0) * 4));
        float vv0 = (s0 + 0 <= t) ? v[0] : -1e30f;
        float vv1 = (s0 + 1 <= t) ? v[1] : -1e30f;
        float vv2 = (s0 + 2 <= t) ? v[2] : -1e30f;
        float vv3 = (s0 + 3 <= t) ? v[3] : -1e30f;
        float m = fmaxf(fmaxf(vv0, vv1), fmaxf(vv2, vv3));
        m = fmaxf(m, __shfl_xor(m, 1));
        m = fmaxf(m, __shfl_xor(m, 2));
        m = fmaxf(m, __shfl_xor(m, 4));
        float e0 = __expf(vv0 - m), e1 = __expf(vv1 - m), e2 = __expf(vv2 - m), e3 = __expf(vv3 - m);
        float sum = e0 + e1 + e2 + e3;
        sum += __shfl_xor(sum, 1);
        sum += __shfl_xor(sum, 2);
        sum += __shfl_xor(sum, 4);
        float inv = 1.0f / sum;
        unsigned int w0 = ((unsigned int)f2bf(e1 * inv) << 16) | f2bf(e0 * inv);
        unsigned int w1 = ((unsigned int)f2bf(e3 * inv) << 16) | f2bf(e2 * inv);
        unsigned off = ((unsigned)((p * 32 + t) * 64 + s0 * 2)) ^ (((unsigned)(t & 3)) << 4);
        i32x2 pv; pv[0] = (int)w0; pv[1] = (int)w1;
        *(i32x2*)(lds + PT0 + off) = pv;
    }
    __syncthreads();

    // ---- phase E: u^T = h^T * Wpv^T (per wave 64 o-cols), write U[o][n] over gT ----
    {
        f32x4 acc[4][4];
#pragma unroll
        for (int mt = 0; mt < 4; ++mt)
#pragma unroll
            for (int of = 0; of < 4; ++of) acc[mt][of] = fzero();
        const unsigned short* wbase = Wpv + (size_t)(wid * 64 + lo) * 512 + hi * 8;
        bf16x8 a0[4], b0v[4], a1[4], b1v[4];
        load_h4(a0, lds + HT0, lo, hi, 0);
        load_w4(b0v, wbase, 0);
#pragma unroll 2
        for (int kk = 0; kk < 8; ++kk) {
            int k0 = kk * 64;
            load_h4(a1, lds + HT0, lo, hi, k0 + 32);
            load_w4(b1v, wbase, k0 + 32);
            mfma16(acc, a0, b0v);
            if (kk < 7) {
                load_h4(a0, lds + HT0, lo, hi, k0 + 64);
                load_w4(b0v, wbase, k0 + 64);
            }
            mfma16(acc, a1, b1v);
        }
#pragma unroll
        for (int mt = 0; mt < 4; ++mt)
#pragma unroll
            for (int of = 0; of < 4; ++of) {
                int o = wid * 64 + of * 16 + lo;
                int n0 = mt * 16 + hi * 4;
                unsigned int w0 = ((unsigned int)f2bf(acc[mt][of][1]) << 16) | f2bf(acc[mt][of][0]);
                unsigned int w1 = ((unsigned int)f2bf(acc[mt][of][3]) << 16) | f2bf(acc[mt][of][2]);
                unsigned off = ((unsigned)(o * 128 + n0 * 2)) ^ (((unsigned)(o & 7)) << 4);
                i32x2 pv; pv[0] = (int)w0; pv[1] = (int)w1;
                *(i32x2*)(lds + GT0 + off) = pv;
            }
    }
    __syncthreads();   // all hT reads done; U visible

    // ---- phase F: out^T[n][o] = P * u^T   + phase G: epilogue ----
    {
        f32x4 oacc[4][4];
#pragma unroll
        for (int rt = 0; rt < 4; ++rt) {
            int p = rt >> 1;
            int ar = rt * 16 + lo;                      // = p*32 + (rt&1)*16 + lo
            unsigned aoff = ((unsigned)(ar * 64 + hi * 16)) ^ (((unsigned)(ar & 3)) << 4);
            bf16x8 a = *(const bf16x8*)(lds + PT0 + aoff);
#pragma unroll
            for (int of = 0; of < 4; ++of) {
                int o = wid * 64 + of * 16 + lo;
                unsigned boff = ((unsigned)(o * 128 + (p * 32 + hi * 8) * 2)) ^ (((unsigned)(o & 7)) << 4);
                bf16x8 b = *(const bf16x8*)(lds + GT0 + boff);
                oacc[rt][of] = __builtin_amdgcn_mfma_f32_16x16x32_bf16(a, b, fzero(), 0, 0, 0);
            }
        }
        unsigned otb = HT0 + (unsigned)wid * 8192u;     // per-wave Ot over dead hT
#pragma unroll
        for (int rt = 0; rt < 4; ++rt)
#pragma unroll
            for (int of = 0; of < 4; ++of) {
                int oc = of * 16 + lo;
                int n0 = rt * 16 + hi * 4;
                unsigned int w0 = ((unsigned int)f2bf(oacc[rt][of][1]) << 16) | f2bf(oacc[rt][of][0]);
                unsigned int w1 = ((unsigned int)f2bf(oacc[rt][of][3]) << 16) | f2bf(oacc[rt][of][2]);
                unsigned off = ((unsigned)(oc * 128 + n0 * 2)) ^ (((unsigned)(oc & 7)) << 4);
                i32x2 pv; pv[0] = (int)w0; pv[1] = (int)w1;
                *(i32x2*)(lds + otb + off) = pv;
            }
        int p_ = lane >> 5, ohi = (lane >> 2) & 7, tq = lane & 3;
        size_t pixg = (size_t)(pix0 + p_);
#pragma unroll
        for (int i = 0; i < 8; ++i) {
            int o = i * 8 + ohi;
            unsigned off = ((unsigned)(o * 128 + (p_ * 32 + tq * 8) * 2)) ^ (((unsigned)(o & 7)) << 4);
            i32x4 v = *(const i32x4*)(lds + otb + off);
            *(i32x4*)(OA + pixg * 16384 + (size_t)(wid * 64 + o) * 32 + tq * 8) = v;
        }
    }
}

// ---------------------------------------------------------------------------
// k_output: out[b][c][t][h][w] = x + OA[pix][c][t]   (transpose back via LDS)
// block = (bb, h, c-chunk of 16); 512 threads; 32KB LDS.
// ---------------------------------------------------------------------------
__global__ __launch_bounds__(512) void k_output(
    const float* __restrict__ x, const unsigned short* __restrict__ OA, float* __restrict__ out)
{
    int bx = blockIdx.x;                  // 4096 = 4*32*32
    int cbk = bx & 31;
    int h = (bx >> 5) & 31;
    int bb = bx >> 10;
    int c0 = cbk * 16;
    int tid = threadIdx.x;
    extern __shared__ char lds[];

#pragma unroll
    for (int it = 0; it < 4; ++it) {
        int chunk = it * 512 + tid;       // 2048 x 16B
        int pix = chunk >> 6;
        int rem = chunk & 63;
        int c = rem >> 2;
        int th = rem & 3;
        size_t pixg = ((size_t)bb * 32 + h) * 32 + pix;
        i32x4 v = *(const i32x4*)(OA + pixg * 16384 + (size_t)(c0 + c) * 32 + th * 8);
        unsigned Kx = ((unsigned)(pix & 31)) << 2;
        unsigned base = (unsigned)(pix * 1024 + c * 64 + th * 16);
        *(unsigned int*)(lds + ((base + 0u) ^ Kx))  = (unsigned int)v[0];
        *(unsigned int*)(lds + ((base + 4u) ^ Kx))  = (unsigned int)v[1];
        *(unsigned int*)(lds + ((base + 8u) ^ Kx))  = (unsigned int)v[2];
        *(unsigned int*)(lds + ((base + 12u) ^ Kx)) = (unsigned int)v[3];
    }
    __syncthreads();
#pragma unroll
    for (int it = 0; it < 8; ++it) {
        int flat4 = it * 512 + tid;       // 4096 float4
        int c = flat4 >> 8;
        int rem = flat4 & 255;
        int t = rem >> 3, w4 = rem & 7;
        size_t gidx = (((size_t)(bb * 512 + c0 + c)) * 32 + t) * 1024 + h * 32 + w4 * 4;
        float4 xv = *(const float4*)(x + gidx);
        float4 ov;
        {
            int pix = w4 * 4 + 0;
            unsigned off = ((unsigned)(pix * 1024 + c * 64 + t * 2)) ^ (((unsigned)(pix & 31)) << 2);
            ov.x = xv.x + bf2f(*(const unsigned short*)(lds + off));
        }
        {
            int pix = w4 * 4 + 1;
            unsigned off = ((unsigned)(pix * 1024 + c * 64 + t * 2)) ^ (((unsigned)(pix & 31)) << 2);
            ov.y = xv.y + bf2f(*(const unsigned short*)(lds + off));
        }
        {
            int pix = w4 * 4 + 2;
            unsigned off = ((unsigned)(pix * 1024 + c * 64 + t * 2)) ^ (((unsigned)(pix & 31)) << 2);
            ov.z = xv.z + bf2f(*(const unsigned short*)(lds + off));
        }
        {
            int pix = w4 * 4 + 3;
            unsigned off = ((unsigned)(pix * 1024 + c * 64 + t * 2)) ^ (((unsigned)(pix & 31)) << 2);
            ov.w = xv.w + bf2f(*(const unsigned short*)(lds + off));
        }
        *(float4*)(out + gidx) = ov;
    }
}

// ---------------------------------------------------------------------------
extern "C" void kernel_launch(void* const* d_in, const int* in_sizes, int n_in,
                              void* d_out, int out_size, void* d_ws, size_t ws_size,
                              hipStream_t stream)
{
    const float* x     = (const float*)d_in[0];
    const float* gamma = (const float*)d_in[1];
    const float* beta  = (const float*)d_in[2];
    const float* wq    = (const float*)d_in[3];
    const float* wk    = (const float*)d_in[4];
    const float* wv    = (const float*)d_in[5];
    const float* wproj = (const float*)d_in[6];
    float* out = (float*)d_out;

    char* ws = (char*)d_ws;
    unsigned short* Hbuf = (unsigned short*)ws;                         // 128MB, Hraw then OA (in-place)
    unsigned short* Wqk  = (unsigned short*)(ws + 134217728);           // 512KB
    unsigned short* Wpv  = (unsigned short*)(ws + 134217728 + 524288);  // 512KB
    float* sums = (float*)(ws + 134217728 + 1048576);                   // 256 floats
    float* mr   = (float*)(ws + 134217728 + 1048576 + 1024);            // 256 floats

    hipMemsetAsync(sums, 0, 256 * sizeof(float), stream);

    hipFuncSetAttribute((const void*)k_transpose_stats, hipFuncAttributeMaxDynamicSharedMemorySize, 65536 + 128);
    hipFuncSetAttribute((const void*)k_attn, hipFuncAttributeMaxDynamicSharedMemorySize, K3_LDS);

    kw_weights<<<dim3(128), dim3(256), 0, stream>>>(wq, wk, wproj, wv, Wqk, Wpv);
    k_transpose_stats<<<dim3(2048), dim3(512), 65536 + 128, stream>>>(x, Hbuf, sums);
    k_finalize<<<dim3(1), dim3(128), 0, stream>>>(sums, mr);
    k_attn<<<dim3(2048), dim3(512), K3_LDS, stream>>>(Hbuf, Wqk, Wpv, gamma, beta, mr, Hbuf);
    k_output<<<dim3(4096), dim3(512), 32768, stream>>>(x, Hbuf, out);
}